// Round 2
// baseline (298.433 us; speedup 1.0000x reference)
//
#include <hip/hip_runtime.h>
#include <stdint.h>

#define N 1024
#define BATCH 32
#define NFILL 1024   // fill blocks: 1024 blocks x 128 KiB span = 128 MiB output

// ---------------------------------------------------------------------------
// Init: zero the fill-completion counter (workspace is re-poisoned each
// iteration with unknown bytes, so it must be cleared by us).
// ---------------------------------------------------------------------------
__global__ __launch_bounds__(64) void init_kernel(int* __restrict__ counter) {
    if (threadIdx.x == 0) *counter = 0;
}

// ---------------------------------------------------------------------------
// Mega kernel.
//   Blocks [BATCH, BATCH+NFILL): zero-fill the 128 MiB output with streaming
//     dwordx4 stores, then release-increment the counter (threadfence +
//     __syncthreads + release atomic: canonical producer pattern).
//   Blocks [0, BATCH): one block per batch row.
//     Phase 1: in-block counting sort (u64 keys in LDS, each thread counts
//              its 4 elements against all 1024 keys) -> positions in regs.
//     Phase 2: scatter to sorted order in LDS, centered y, wave scans,
//              serial PAV over runs (verbatim verified pipeline).
//     Phase 3: acquire-spin until counter == NFILL (fill done), then write
//              the <=2 nonzeros per output row (width-2 triangle at floor(r)).
//   No pos/ranks global round-trip; count+scan+PAV hide under the fill's
//   ~21 us of store traffic. Fill blocks never wait -> no deadlock; only 32
//   rank blocks spin (cannot exhaust 3 blocks/CU x 256 CU residency).
// ---------------------------------------------------------------------------
__global__ __launch_bounds__(256) void mega_kernel(const float* __restrict__ x,
                                                   float* __restrict__ out,
                                                   int* __restrict__ counter) {
    if (blockIdx.x >= BATCH) {
        // ---- zero-fill branch: contiguous 128 KiB span per block ----------
        const int fid = blockIdx.x - BATCH;
        float4* o = reinterpret_cast<float4*>(out) + (size_t)fid * 8192 + threadIdx.x;
        const float4 z = make_float4(0.0f, 0.0f, 0.0f, 0.0f);
        #pragma unroll
        for (int i = 0; i < 32; ++i) o[i * 256] = z;
        __threadfence();          // each thread: own stores visible agent-wide
        __syncthreads();          // all threads' fences done
        if (threadIdx.x == 0)
            __hip_atomic_fetch_add(counter, 1, __ATOMIC_RELEASE, __HIP_MEMORY_SCOPE_AGENT);
        return;
    }

    // ---- rank branch (one block per batch row) ----------------------------
    __shared__ uint64_t keys[N];        // 8 KB   (count phase)
    __shared__ float    ss[N];          // sorted values (descending)
    __shared__ float    yv[N];          // y = s + (i - 512)  (centered)
    __shared__ double   csum[N];        // inclusive prefix of yv (double)
    __shared__ int      segid[N];       // run id per sorted position
    __shared__ int      run_start[N+1]; // run boundary positions
    __shared__ float    run_mean[N];    // final (centered) mean per run
    __shared__ double   stk_sum[N];     // PAV stack: block sums
    __shared__ int      stk_cnt[N];     // PAV stack: element counts
    __shared__ int      stk_runs[N];    // PAV stack: runs per block
    __shared__ double   wsumD[4];
    __shared__ int      wsumI[4];

    const int b = blockIdx.x;
    const int t = threadIdx.x;
    const int j0 = t << 2;
    const int lane = t & 63;
    const int wid = t >> 6;

    // ---- phase 1: load row, build keys, count positions in-block ----------
    const float4 xq = reinterpret_cast<const float4*>(x + b * N)[t];
    const float vv[4] = {xq.x, xq.y, xq.z, xq.w};
    uint64_t kk[4];
    {
        #pragma unroll
        for (int e = 0; e < 4; ++e) {
            uint32_t u = __float_as_uint(vv[e]);
            u ^= (u & 0x80000000u) ? 0xFFFFFFFFu : 0x80000000u;  // monotone map
            // descending, stable: position = #{k : key_k > key_j}
            kk[e] = (((uint64_t)u) << 10) | (uint64_t)(1023 - (j0 + e));
            keys[j0 + e] = kk[e];
        }
    }
    __syncthreads();

    int c[4] = {0, 0, 0, 0};
    for (int k = 0; k < N; k += 4) {
        const uint64_t k0 = keys[k];       // broadcast reads, conflict-free
        const uint64_t k1 = keys[k + 1];
        const uint64_t k2 = keys[k + 2];
        const uint64_t k3 = keys[k + 3];
        #pragma unroll
        for (int e = 0; e < 4; ++e) {
            c[e] += (int)(k0 > kk[e]);
            c[e] += (int)(k1 > kk[e]);
            c[e] += (int)(k2 > kk[e]);
            c[e] += (int)(k3 > kk[e]);
        }
    }
    // scatter into sorted order
    ss[c[0]] = xq.x; ss[c[1]] = xq.y; ss[c[2]] = xq.z; ss[c[3]] = xq.w;
    __syncthreads();

    // ---- phase 2a: y[i] = s[i] + (i - 512)  (centered for precision) ------
    float4 yq;
    {
        const float4 sq = reinterpret_cast<const float4*>(ss)[t];
        yq.x = sq.x + (float)(j0 - 512);
        yq.y = sq.y + (float)(j0 - 511);
        yq.z = sq.z + (float)(j0 - 510);
        yq.w = sq.w + (float)(j0 - 509);
        reinterpret_cast<float4*>(yv)[t] = yq;
    }
    __syncthreads();

    // ---- phase 2b: descent flags + thread-local inclusive scans -----------
    const float ye[4] = {yq.x, yq.y, yq.z, yq.w};
    int    fl[4];          // raw flags
    int    lf[4];          // local inclusive flag scan
    double lys[4];         // local inclusive y scan
    {
        float prev = (j0 == 0) ? -1.0e30f : yv[j0 - 1];
        double accy = 0.0; int accf = 0;
        #pragma unroll
        for (int e = 0; e < 4; ++e) {
            const int f = (prev > ye[e]) ? 1 : 0;   // strict descent = run start
            prev = ye[e];
            fl[e] = f;
            accf += f;             lf[e]  = accf;
            accy += (double)ye[e]; lys[e] = accy;
        }
    }
    // wave-level inclusive scan of thread totals
    double vy = lys[3]; int vf = lf[3];
    #pragma unroll
    for (int off = 1; off < 64; off <<= 1) {
        const double oy = __shfl_up(vy, off);
        const int    of = __shfl_up(vf, off);
        if (lane >= off) { vy += oy; vf += of; }
    }
    if (lane == 63) { wsumD[wid] = vy; wsumI[wid] = vf; }
    __syncthreads();
    // cross-wave offsets, per-element inclusive values
    {
        double basey = vy - lys[3]; int basef = vf - lf[3];
        for (int w = 0; w < wid; ++w) { basey += wsumD[w]; basef += wsumI[w]; }
        #pragma unroll
        for (int e = 0; e < 4; ++e) {
            const int p   = j0 + e;
            const int seg = basef + lf[e];
            segid[p] = seg;
            csum[p]  = basey + lys[e];
            if (fl[e]) run_start[seg] = p;   // unique writer per seg >= 1
        }
        if (t == 0) run_start[0] = 0;
    }
    __syncthreads();

    // ---- phase 2c: PAV over runs (thread 0; R tiny for near-monotone y) ---
    if (t == 0) {
        const int R = segid[N - 1] + 1;
        run_start[R] = N;
        int sp = 0;
        for (int r = 0; r < R; ++r) {
            const int a   = run_start[r];
            const int bnd = run_start[r + 1];
            double s = csum[bnd - 1] - ((a > 0) ? csum[a - 1] : 0.0);
            int    cc = bnd - a;
            int    nr = 1;
            // pool while top block's mean < new block's mean
            while (sp > 0 && s * (double)stk_cnt[sp - 1] > stk_sum[sp - 1] * (double)cc) {
                s  += stk_sum[sp - 1];
                cc += stk_cnt[sp - 1];
                nr += stk_runs[sp - 1];
                --sp;
            }
            stk_sum[sp] = s; stk_cnt[sp] = cc; stk_runs[sp] = nr; ++sp;
        }
        int rc = 0;
        for (int e2 = 0; e2 < sp; ++e2) {
            const float m = (float)(stk_sum[e2] / (double)stk_cnt[e2]);
            for (int q2 = 0; q2 < stk_runs[e2]; ++q2) run_mean[rc++] = m;
        }
    }
    __syncthreads();

    // ---- phase 3: wait for fill completion, scatter <=2 nonzeros/row ------
    if (t == 0) {
        while (__hip_atomic_load(counter, __ATOMIC_ACQUIRE, __HIP_MEMORY_SCOPE_AGENT) < NFILL)
            __builtin_amdgcn_s_sleep(8);
    }
    __syncthreads();

    #pragma unroll
    for (int e = 0; e < 4; ++e) {
        // rank for original column j0+e  (same arithmetic as verified rounds)
        const float r = vv[e] - run_mean[segid[c[e]]] + 512.0f;
        const float f = floorf(r);
        const int   i1 = (int)f;            // nonzero at i+1 == i1 and i1+1
        const float frac = r - f;
        float* o = out + (size_t)(b * N + j0 + e) * N;
        if (i1 >= 1 && i1 <= N) o[i1 - 1] = 1.0f - frac;
        if (i1 >= 0 && i1 <  N) o[i1]     = frac;
    }
}

extern "C" void kernel_launch(void* const* d_in, const int* in_sizes, int n_in,
                              void* d_out, int out_size, void* d_ws, size_t ws_size,
                              hipStream_t stream) {
    const float* x = (const float*)d_in[0];
    float* out = (float*)d_out;
    int* counter = (int*)d_ws;

    init_kernel<<<1, 64, 0, stream>>>(counter);
    mega_kernel<<<BATCH + NFILL, 256, 0, stream>>>(x, out, counter);
}

// Round 3
// 139.817 us; speedup vs baseline: 2.1345x; 2.1345x over previous
//
#include <hip/hip_runtime.h>
#include <stdint.h>

#define N 1024
#define BATCH 32
#define NFILL 4096   // fill blocks: 4096 x 32 KiB span = 128 MiB output

// ---------------------------------------------------------------------------
// Fused kernel.
//   Blocks [BATCH, BATCH+NFILL): zero-fill the 128 MiB output with plain
//     streaming dwordx4 stores (NO fence, NO atomics — R2 showed agent-scope
//     release machinery collapses store BW 9x on non-coherent XCD L2s).
//     Ordering with the scatter pass is provided by the kernel boundary.
//   Blocks [0, BATCH): one block per batch row (verified R2 pipeline):
//     Phase 1: in-block counting sort (u64 keys in LDS) -> positions in regs.
//     Phase 2: scatter to sorted order in LDS, centered y, wave scans,
//              serial PAV over runs.
//     Output: ranks[b*N + j] to workspace (128 KB).
//   Rank blocks are FIRST in the grid so they dispatch immediately and hide
//   entirely under the fill's ~22 us of store traffic.
// ---------------------------------------------------------------------------
__global__ __launch_bounds__(256) void fused_kernel(const float* __restrict__ x,
                                                    float* __restrict__ out,
                                                    float* __restrict__ ranks) {
    if (blockIdx.x >= BATCH) {
        // ---- zero-fill branch: contiguous 32 KiB span per block -----------
        const int fid = blockIdx.x - BATCH;
        float4* o = reinterpret_cast<float4*>(out) + (size_t)fid * 2048 + threadIdx.x;
        const float4 z = make_float4(0.0f, 0.0f, 0.0f, 0.0f);
        #pragma unroll
        for (int i = 0; i < 8; ++i) o[i * 256] = z;
        return;
    }

    // ---- rank branch (one block per batch row) ----------------------------
    __shared__ uint64_t keys[N];        // 8 KB   (count phase)
    __shared__ float    ss[N];          // sorted values (descending)
    __shared__ float    yv[N];          // y = s + (i - 512)  (centered)
    __shared__ double   csum[N];        // inclusive prefix of yv (double)
    __shared__ int      segid[N];       // run id per sorted position
    __shared__ int      run_start[N+1]; // run boundary positions
    __shared__ float    run_mean[N];    // final (centered) mean per run
    __shared__ double   stk_sum[N];     // PAV stack: block sums
    __shared__ int      stk_cnt[N];     // PAV stack: element counts
    __shared__ int      stk_runs[N];    // PAV stack: runs per block
    __shared__ double   wsumD[4];
    __shared__ int      wsumI[4];

    const int b = blockIdx.x;
    const int t = threadIdx.x;
    const int j0 = t << 2;
    const int lane = t & 63;
    const int wid = t >> 6;

    // ---- phase 1: load row, build keys, count positions in-block ----------
    const float4 xq = reinterpret_cast<const float4*>(x + b * N)[t];
    const float vv[4] = {xq.x, xq.y, xq.z, xq.w};
    uint64_t kk[4];
    {
        #pragma unroll
        for (int e = 0; e < 4; ++e) {
            uint32_t u = __float_as_uint(vv[e]);
            u ^= (u & 0x80000000u) ? 0xFFFFFFFFu : 0x80000000u;  // monotone map
            // descending, stable: position = #{k : key_k > key_j}
            kk[e] = (((uint64_t)u) << 10) | (uint64_t)(1023 - (j0 + e));
            keys[j0 + e] = kk[e];
        }
    }
    __syncthreads();

    int c[4] = {0, 0, 0, 0};
    for (int k = 0; k < N; k += 4) {
        const uint64_t k0 = keys[k];       // broadcast reads, conflict-free
        const uint64_t k1 = keys[k + 1];
        const uint64_t k2 = keys[k + 2];
        const uint64_t k3 = keys[k + 3];
        #pragma unroll
        for (int e = 0; e < 4; ++e) {
            c[e] += (int)(k0 > kk[e]);
            c[e] += (int)(k1 > kk[e]);
            c[e] += (int)(k2 > kk[e]);
            c[e] += (int)(k3 > kk[e]);
        }
    }
    // scatter into sorted order
    ss[c[0]] = xq.x; ss[c[1]] = xq.y; ss[c[2]] = xq.z; ss[c[3]] = xq.w;
    __syncthreads();

    // ---- phase 2a: y[i] = s[i] + (i - 512)  (centered for precision) ------
    float4 yq;
    {
        const float4 sq = reinterpret_cast<const float4*>(ss)[t];
        yq.x = sq.x + (float)(j0 - 512);
        yq.y = sq.y + (float)(j0 - 511);
        yq.z = sq.z + (float)(j0 - 510);
        yq.w = sq.w + (float)(j0 - 509);
        reinterpret_cast<float4*>(yv)[t] = yq;
    }
    __syncthreads();

    // ---- phase 2b: descent flags + thread-local inclusive scans -----------
    const float ye[4] = {yq.x, yq.y, yq.z, yq.w};
    int    fl[4];          // raw flags
    int    lf[4];          // local inclusive flag scan
    double lys[4];         // local inclusive y scan
    {
        float prev = (j0 == 0) ? -1.0e30f : yv[j0 - 1];
        double accy = 0.0; int accf = 0;
        #pragma unroll
        for (int e = 0; e < 4; ++e) {
            const int f = (prev > ye[e]) ? 1 : 0;   // strict descent = run start
            prev = ye[e];
            fl[e] = f;
            accf += f;             lf[e]  = accf;
            accy += (double)ye[e]; lys[e] = accy;
        }
    }
    // wave-level inclusive scan of thread totals
    double vy = lys[3]; int vf = lf[3];
    #pragma unroll
    for (int off = 1; off < 64; off <<= 1) {
        const double oy = __shfl_up(vy, off);
        const int    of = __shfl_up(vf, off);
        if (lane >= off) { vy += oy; vf += of; }
    }
    if (lane == 63) { wsumD[wid] = vy; wsumI[wid] = vf; }
    __syncthreads();
    // cross-wave offsets, per-element inclusive values
    {
        double basey = vy - lys[3]; int basef = vf - lf[3];
        for (int w = 0; w < wid; ++w) { basey += wsumD[w]; basef += wsumI[w]; }
        #pragma unroll
        for (int e = 0; e < 4; ++e) {
            const int p   = j0 + e;
            const int seg = basef + lf[e];
            segid[p] = seg;
            csum[p]  = basey + lys[e];
            if (fl[e]) run_start[seg] = p;   // unique writer per seg >= 1
        }
        if (t == 0) run_start[0] = 0;
    }
    __syncthreads();

    // ---- phase 2c: PAV over runs (thread 0; R tiny for near-monotone y) ---
    if (t == 0) {
        const int R = segid[N - 1] + 1;
        run_start[R] = N;
        int sp = 0;
        for (int r = 0; r < R; ++r) {
            const int a   = run_start[r];
            const int bnd = run_start[r + 1];
            double s = csum[bnd - 1] - ((a > 0) ? csum[a - 1] : 0.0);
            int    cc = bnd - a;
            int    nr = 1;
            // pool while top block's mean < new block's mean
            while (sp > 0 && s * (double)stk_cnt[sp - 1] > stk_sum[sp - 1] * (double)cc) {
                s  += stk_sum[sp - 1];
                cc += stk_cnt[sp - 1];
                nr += stk_runs[sp - 1];
                --sp;
            }
            stk_sum[sp] = s; stk_cnt[sp] = cc; stk_runs[sp] = nr; ++sp;
        }
        int rc = 0;
        for (int e2 = 0; e2 < sp; ++e2) {
            const float m = (float)(stk_sum[e2] / (double)stk_cnt[e2]);
            for (int q2 = 0; q2 < stk_runs[e2]; ++q2) run_mean[rc++] = m;
        }
    }
    __syncthreads();

    // ---- write ranks: ranks[j] = x[j] - (sol - 512) -----------------------
    float4 r4;
    r4.x = vv[0] - run_mean[segid[c[0]]] + 512.0f;
    r4.y = vv[1] - run_mean[segid[c[1]]] + 512.0f;
    r4.z = vv[2] - run_mean[segid[c[2]]] + 512.0f;
    r4.w = vv[3] - run_mean[segid[c[3]]] + 512.0f;
    reinterpret_cast<float4*>(ranks + b * N)[t] = r4;
}

// ---------------------------------------------------------------------------
// Kernel S: scatter the <=2 nonzeros per output row (verified R0/R1).
//   out[b,j,i] = relu(1 - |r - (i+1)|) is a width-2 triangle: nonzero only at
//   i+1 = floor(r) (value 1-frac) and i+1 = floor(r)+1 (value frac).
//   Numerically identical to the dense per-element computation.
//   One thread per (b,j) row; coalesced rank load, <=2 scattered 4 B stores.
// ---------------------------------------------------------------------------
__global__ __launch_bounds__(256) void scatter_kernel(const float* __restrict__ ranks,
                                                      float* __restrict__ out) {
    const int row = blockIdx.x * 256 + threadIdx.x;   // row = b*N + j, 32768 rows
    const float r = ranks[row];
    const float f = floorf(r);
    const int   i1 = (int)f;            // nonzero at i+1 == i1 and i+1 == i1+1
    const float frac = r - f;
    float* o = out + (size_t)row * N;
    if (i1 >= 1 && i1 <= N) o[i1 - 1] = 1.0f - frac;
    if (i1 >= 0 && i1 <  N) o[i1]     = frac;
}

extern "C" void kernel_launch(void* const* d_in, const int* in_sizes, int n_in,
                              void* d_out, int out_size, void* d_ws, size_t ws_size,
                              hipStream_t stream) {
    const float* x = (const float*)d_in[0];
    float* out = (float*)d_out;
    float* ranks = (float*)d_ws;                      // 32K floats = 128 KB

    fused_kernel<<<BATCH + NFILL, 256, 0, stream>>>(x, out, ranks);
    scatter_kernel<<<(BATCH * N) / 256, 256, 0, stream>>>(ranks, out);
}